// Round 8
// baseline (190.316 us; speedup 1.0000x reference)
//
#include <hip/hip_runtime.h>
#include <math.h>

#define BATCH 32
#define HQ 32
#define HKV 8
#define DHEAD 128
#define BS 16
#define MAXB 128
#define G 4
#define LMAX 2048
#define CHUNK 64               // positions per chunk-block (4 cache blocks)
#define NCH (LMAX / CHUNK)     // 32 chunks per batch
#define NGMAX (CHUNK / 4)      // 16 groups of 4 positions
#define NBKV (BATCH * HKV)
#define BLKF (BS * HKV * DHEAD)   // floats per cache block = 16384

#define SCALE_LOG2E 0.12752740305928724f  // (1/sqrt(128)) * log2(e)

typedef float v2f __attribute__((ext_vector_type(2)));

__device__ __forceinline__ v2f pk_fma(v2f a, v2f b, v2f c) {
    v2f d;
    asm("v_pk_fma_f32 %0, %1, %2, %3" : "=v"(d) : "v"(a), "v"(b), "v"(c));
    return d;
}
__device__ __forceinline__ v2f pk_mul(v2f a, v2f b) {
    v2f d;
    asm("v_pk_mul_f32 %0, %1, %2" : "=v"(d) : "v"(a), "v"(b));
    return d;
}
__device__ __forceinline__ float fexp2(float x) {
    float r;
    asm("v_exp_f32 %0, %1" : "=v"(r) : "v"(x));
    return r;
}

// ---------------- chunk kernel: one (b, 64-position chunk), all 8 kv ----------------
__global__ __launch_bounds__(256) void paged_attn_chunk(
    const float* __restrict__ query,       // [B, HQ, D]
    const float* __restrict__ k_cache,
    const float* __restrict__ v_cache,
    const int*   __restrict__ block_table,
    const int*   __restrict__ context_lens,
    float*       __restrict__ wsacc,       // [B][NCH][HKV][G][D]
    float*       __restrict__ wsl)         // [B][NCH][HKV][G]
{
    const int c = blockIdx.x & (NCH - 1);
    const int b = blockIdx.x >> 5;
    const int pos = context_lens[b];
    const int c0  = c * CHUNK;
    if (c0 >= pos) return;                 // position pos itself handled in combine

    const int tid  = threadIdx.x;
    const int w    = tid >> 6;             // wave = q-head within group
    const int lane = tid & 63;
    const int kvq  = lane >> 3;            // kv head owned by this lane
    const int sub  = lane & 7;             // 16-float d-slice: sub*16 .. +15

    // LDS: 64 KB. During main loop: K buf0 [0,4096), K buf1 [4096,8192),
    // V buf0 [8192,12288), V buf1 [12288,16384) (float indices).
    // Preamble aliases: roped q in [0,4096), cos/sin at [4096,4224).
    __shared__ float smem[16384];
    float* s_cos = &smem[4096];
    float* s_sin = &smem[4160];

    // ---- RoPE tables ----
    if (tid < 64) {
        float invf = exp2f((float)tid * -0.20762050593046014f); // 10000^(-t/64)
        float ang  = (float)pos * invf;
        s_cos[tid] = cosf(ang);
        s_sin[tid] = sinf(ang);
    }
    __syncthreads();

    // ---- roped, scaled q -> smem[0,4096) ----
    for (int idx = tid; idx < HQ * DHEAD; idx += 256) {
        int head = idx >> 7, d = idx & 127;
        const float* qp = query + ((size_t)b * HQ + head) * DHEAD;
        float x = qp[d], r;
        if (d < 64) r = x * s_cos[d]      - qp[d + 64] * s_sin[d];
        else        r = x * s_cos[d - 64] + qp[d - 64] * s_sin[d - 64];
        smem[idx] = r * SCALE_LOG2E;
    }
    __syncthreads();

    // ---- q fragment to registers: head = kvq*4 + w, floats sub*16..+15 ----
    v2f q2[8];
    {
        const int qb = (kvq * G + w) * DHEAD + sub * 16;
        #pragma unroll
        for (int j = 0; j < 4; ++j) {
            float4 t4 = *(const float4*)&smem[qb + j * 4];
            q2[2 * j]     = v2f{t4.x, t4.y};
            q2[2 * j + 1] = v2f{t4.z, t4.w};
        }
    }
    // RACE FIX (round 8): K buf0 aliases the roped-q region [0,4096).
    // All waves must finish reading q2 before any wave's DS_WRITE(0) below.
    __syncthreads();

    // block-table entries for the 4 cache blocks of this chunk (wave-uniform)
    const int tb0 = __builtin_amdgcn_readfirstlane(block_table[b * MAXB + c * 4 + 0]);
    const int tb1 = __builtin_amdgcn_readfirstlane(block_table[b * MAXB + c * 4 + 1]);
    const int tb2 = __builtin_amdgcn_readfirstlane(block_table[b * MAXB + c * 4 + 2]);
    const int tb3 = __builtin_amdgcn_readfirstlane(block_table[b * MAXB + c * 4 + 3]);

    const int ng = min(NGMAX, (pos - c0 + 3) >> 2);   // groups of 4 positions

    // swizzled read offsets (float idx) for j=0..3 within a [4pos][8kv][128d] buffer
    int O[4];
    {
        const int A = kvq * 128 + sub * 16;
        const int X = kvq << 2;
        #pragma unroll
        for (int j = 0; j < 4; ++j) O[j] = (A + j * 4) ^ X;
    }

    const float* kvbase = (w < 2) ? k_cache : v_cache;
    const int wb = (w & 1) * 2048;          // this wave's half (floats) of a 16KB stream

    float4 st[8];                            // staging registers (8 KB / wave)

#define LOAD_REGS(GG) do {                                                     \
        int gg_ = (GG) >> 2;                                                   \
        int blk_ = gg_ == 0 ? tb0 : gg_ == 1 ? tb1 : gg_ == 2 ? tb2 : tb3;     \
        const float* gsrc_ = kvbase + (size_t)blk_ * BLKF +                    \
                             ((GG) & 3) * 4096 + wb + lane * 4;                \
        _Pragma("unroll")                                                      \
        for (int i = 0; i < 8; ++i) st[i] = *(const float4*)(gsrc_ + i * 256); \
    } while (0)

#define DS_WRITE(BUF) do {                                                     \
        const int rb_ = (w < 2 ? 0 : 8192) + (BUF) * 4096;                     \
        _Pragma("unroll")                                                      \
        for (int i = 0; i < 8; ++i) {                                          \
            int rel_ = wb + i * 256 + lane * 4;                                \
            int sw_  = rel_ ^ (((rel_ >> 7) & 7) << 2);                        \
            *(float4*)&smem[rb_ + sw_] = st[i];                                \
        }                                                                      \
    } while (0)

    v2f acc2[8];
    #pragma unroll
    for (int j = 0; j < 8; ++j) acc2[j] = v2f{0.f, 0.f};
    float lsum = 0.f;

    // prologue
    LOAD_REGS(0);
    DS_WRITE(0);
    if (ng > 1) LOAD_REGS(1);
    __syncthreads();

    for (int g = 0; g < ng; ++g) {
        const int kb = (g & 1) * 4096;
        const int vb = 8192 + (g & 1) * 4096;
        const int pbase = c0 + g * 4;

        #pragma unroll
        for (int ps = 0; ps < 4; ++ps) {
            const int pi = pbase + ps;
            const float4 kA = *(const float4*)&smem[kb + ps * 1024 + O[0]];
            const float4 kB = *(const float4*)&smem[kb + ps * 1024 + O[1]];
            const float4 kC = *(const float4*)&smem[kb + ps * 1024 + O[2]];
            const float4 kD = *(const float4*)&smem[kb + ps * 1024 + O[3]];
            v2f dk = pk_mul(q2[0], v2f{kA.x, kA.y});
            dk = pk_fma(q2[1], v2f{kA.z, kA.w}, dk);
            dk = pk_fma(q2[2], v2f{kB.x, kB.y}, dk);
            dk = pk_fma(q2[3], v2f{kB.z, kB.w}, dk);
            dk = pk_fma(q2[4], v2f{kC.x, kC.y}, dk);
            dk = pk_fma(q2[5], v2f{kC.z, kC.w}, dk);
            dk = pk_fma(q2[6], v2f{kD.x, kD.y}, dk);
            dk = pk_fma(q2[7], v2f{kD.z, kD.w}, dk);
            float dt = dk.x + dk.y;
            dt += __shfl_xor(dt, 1, 64);
            dt += __shfl_xor(dt, 2, 64);
            dt += __shfl_xor(dt, 4, 64);
            const float wg = (pi < pos) ? fexp2(dt) : 0.f;
            lsum += wg;
            const float4 vA = *(const float4*)&smem[vb + ps * 1024 + O[0]];
            const float4 vB = *(const float4*)&smem[vb + ps * 1024 + O[1]];
            const float4 vC = *(const float4*)&smem[vb + ps * 1024 + O[2]];
            const float4 vD = *(const float4*)&smem[vb + ps * 1024 + O[3]];
            const v2f w2 = v2f{wg, wg};
            acc2[0] = pk_fma(w2, v2f{vA.x, vA.y}, acc2[0]);
            acc2[1] = pk_fma(w2, v2f{vA.z, vA.w}, acc2[1]);
            acc2[2] = pk_fma(w2, v2f{vB.x, vB.y}, acc2[2]);
            acc2[3] = pk_fma(w2, v2f{vB.z, vB.w}, acc2[3]);
            acc2[4] = pk_fma(w2, v2f{vC.x, vC.y}, acc2[4]);
            acc2[5] = pk_fma(w2, v2f{vC.z, vC.w}, acc2[5]);
            acc2[6] = pk_fma(w2, v2f{vD.x, vD.y}, acc2[6]);
            acc2[7] = pk_fma(w2, v2f{vD.z, vD.w}, acc2[7]);
        }

        if (g + 1 < ng) {
            __syncthreads();                 // readers done with buf[(g+1)&1]
            DS_WRITE((g + 1) & 1);           // st regs (loaded ~1 group ago) -> LDS
            if (g + 2 < ng) LOAD_REGS(g + 2);// issue early; lands during next compute
            __syncthreads();                 // writes visible
        }
    }

#undef LOAD_REGS
#undef DS_WRITE

    // ---- write partials: each (kv, h, d-slice) owned by exactly one lane ----
    const size_t obase =
        (((size_t)(b * NCH + c) * HKV + kvq) * G + w) * DHEAD + sub * 16;
    #pragma unroll
    for (int j = 0; j < 4; ++j) {
        float4 o4 = make_float4(acc2[2 * j].x, acc2[2 * j].y,
                                acc2[2 * j + 1].x, acc2[2 * j + 1].y);
        *(float4*)&wsacc[obase + j * 4] = o4;
    }
    if (sub == 0)
        wsl[((size_t)(b * NCH + c) * HKV + kvq) * G + w] = lsum;
}

// ---------------- combine: chunk partials + new-token contribution ----------------
__global__ __launch_bounds__(512) void paged_attn_combine(
    const float* __restrict__ query,
    const float* __restrict__ new_k,
    const float* __restrict__ new_v,
    const int*   __restrict__ context_lens,
    const float* __restrict__ wsacc,
    const float* __restrict__ wsl,
    float*       __restrict__ out)
{
    const int bkv = blockIdx.x;
    const int kv  = bkv & 7;
    const int b   = bkv >> 3;
    const int t   = threadIdx.x;
    const int h   = t >> 7;
    const int d   = t & 127;
    const int wv  = t >> 6;

    __shared__ float s_cos[64], s_sin[64], s_kn[DHEAD], s_ps[8];

    const int pos = context_lens[b];
    if (t < 64) {
        float invf = exp2f((float)t * -0.20762050593046014f);
        float ang  = (float)pos * invf;
        s_cos[t] = cosf(ang);
        s_sin[t] = sinf(ang);
    }
    __syncthreads();
    if (t < DHEAD) {
        const float* kp = new_k + ((size_t)b * HKV + kv) * DHEAD;
        float x = kp[t], r;
        if (t < 64) r = x * s_cos[t]      - kp[t + 64] * s_sin[t];
        else        r = x * s_cos[t - 64] + kp[t - 64] * s_sin[t - 64];
        s_kn[t] = r;
    }
    __syncthreads();

    // roped, scaled q for (h, d), then dot with roped k_new
    float rq;
    {
        const float* qp = query + ((size_t)b * HQ + kv * G + h) * DHEAD;
        float x = qp[d];
        if (d < 64) rq = x * s_cos[d]      - qp[d + 64] * s_sin[d];
        else        rq = x * s_cos[d - 64] + qp[d - 64] * s_sin[d - 64];
        rq *= SCALE_LOG2E;
    }
    float part = rq * s_kn[d];
    #pragma unroll
    for (int off = 1; off < 64; off <<= 1) part += __shfl_xor(part, off, 64);
    if ((t & 63) == 0) s_ps[wv] = part;
    __syncthreads();

    const float wnew = fexp2(s_ps[2 * h] + s_ps[2 * h + 1]);

    const int ncc = (pos + CHUNK - 1) >> 6;   // chunks with any position < pos

    float asum = 0.f, lsum = 0.f;
    for (int cc = 0; cc < ncc; cc++) {
        asum += wsacc[(((size_t)(b * NCH + cc) * HKV + kv) * G + h) * DHEAD + d];
        lsum += wsl[((size_t)(b * NCH + cc) * HKV + kv) * G + h];
    }
    const float vnew = new_v[((size_t)b * HKV + kv) * DHEAD + d];
    out[((size_t)b * HQ + kv * G + h) * DHEAD + d] =
        (asum + wnew * vnew) / (lsum + wnew);
}

extern "C" void kernel_launch(void* const* d_in, const int* in_sizes, int n_in,
                              void* d_out, int out_size, void* d_ws, size_t ws_size,
                              hipStream_t stream) {
    const float* query        = (const float*)d_in[0];
    const float* new_k        = (const float*)d_in[1];
    const float* new_v        = (const float*)d_in[2];
    const float* k_cache      = (const float*)d_in[3];
    const float* v_cache      = (const float*)d_in[4];
    const int*   block_table  = (const int*)d_in[5];
    const int*   context_lens = (const int*)d_in[6];
    float* out = (float*)d_out;

    float* wsacc = (float*)d_ws;                                   // B*NCH*HKV*G*D
    float* wsl   = wsacc + (size_t)BATCH * NCH * HKV * G * DHEAD;  // B*NCH*HKV*G

    paged_attn_chunk<<<dim3(BATCH * NCH), dim3(256), 0, stream>>>(
        query, k_cache, v_cache, block_table, context_lens, wsacc, wsl);
    paged_attn_combine<<<dim3(NBKV), dim3(512), 0, stream>>>(
        query, new_k, new_v, context_lens, wsacc, wsl, out);
}

// Round 9
// 88.219 us; speedup vs baseline: 2.1573x; 2.1573x over previous
//
#include <hip/hip_runtime.h>
#include <math.h>

#define BATCH 32
#define HQ 32
#define HKV 8
#define DHEAD 128
#define BS 16
#define MAXB 128
#define G 4
#define LMAX 2048
#define NBKV (BATCH * HKV)
#define BLKF (BS * HKV * DHEAD)     // floats per cache block

#define SCALE_LOG2E 0.12752740305928724f  // (1/sqrt(128)) * log2(e)

typedef float v2f __attribute__((ext_vector_type(2)));

__device__ __forceinline__ v2f pk_fma(v2f a, v2f b, v2f c) {
    v2f d;
    asm("v_pk_fma_f32 %0, %1, %2, %3" : "=v"(d) : "v"(a), "v"(b), "v"(c));
    return d;
}
__device__ __forceinline__ v2f pk_mul(v2f a, v2f b) {
    v2f d;
    asm("v_pk_mul_f32 %0, %1, %2" : "=v"(d) : "v"(a), "v"(b));
    return d;
}
__device__ __forceinline__ float fexp2(float x) {
    float r;
    asm("v_exp_f32 %0, %1" : "=v"(r) : "v"(x));
    return r;
}

// rotate-and-add over each 16-lane row, 4 independent chains.
#define ROR4(N, x0, x1, x2, x3)                                                   \
    asm("s_nop 1\n\t"                                                             \
        "v_add_f32_dpp %0, %0, %0 row_ror:" #N " row_mask:0xf bank_mask:0xf\n\t"  \
        "v_add_f32_dpp %1, %1, %1 row_ror:" #N " row_mask:0xf bank_mask:0xf\n\t"  \
        "v_add_f32_dpp %2, %2, %2 row_ror:" #N " row_mask:0xf bank_mask:0xf\n\t"  \
        "v_add_f32_dpp %3, %3, %3 row_ror:" #N " row_mask:0xf bank_mask:0xf"      \
        : "+v"(x0), "+v"(x1), "+v"(x2), "+v"(x3))

// ---------------- chunk kernel: block = (b, PP positions), wave = kv head ----
// Each 32-lane half owns one position per iteration; lane loads ONE float4 of
// the 512B K row (and V row) -> every load instruction covers two contiguous
// 512B segments, no holes.
template <int PP>
__global__ __launch_bounds__(512) void paged_attn_chunk(
    const float* __restrict__ query,       // [B, HQ, D]
    const float* __restrict__ k_cache,
    const float* __restrict__ v_cache,
    const int*   __restrict__ block_table,
    const int*   __restrict__ context_lens,
    float*       __restrict__ wsacc,       // [B][NCHK][HKV][G][D]
    float*       __restrict__ wsl)         // [B][NCHK][HKV][G]
{
    constexpr int NCHK = LMAX / PP;
    constexpr int NCB  = PP / 16;          // cache blocks per chunk
    constexpr int NIT  = PP / 2;           // iterations (2 positions each)

    const int c = blockIdx.x % NCHK;
    const int b = blockIdx.x / NCHK;
    const int pos = context_lens[b];
    const int c0  = c * PP;
    if (c0 >= pos) return;                 // position 'pos' handled in combine

    const int tid  = threadIdx.x;
    const int w    = tid >> 6;             // wave = kv head (0..7)
    const int lane = tid & 63;
    const int half = lane >> 5;            // which position of the pair
    const int l5   = lane & 31;            // d-slice: floats l5*4 .. +3

    __shared__ float s_q[HQ * DHEAD];      // 16 KB
    __shared__ float s_cos[64], s_sin[64];

    // ---- RoPE tables ----
    if (tid < 64) {
        float invf = exp2f((float)tid * -0.20762050593046014f); // 10000^(-t/64)
        float ang  = (float)pos * invf;
        s_cos[tid] = cosf(ang);
        s_sin[tid] = sinf(ang);
    }
    __syncthreads();

    // ---- roped, scaled q for all 32 heads ----
    for (int idx = tid; idx < HQ * DHEAD; idx += 512) {
        int head = idx >> 7, d = idx & 127;
        const float* qp = query + ((size_t)b * HQ + head) * DHEAD;
        float x = qp[d], r;
        if (d < 64) r = x * s_cos[d]      - qp[d + 64] * s_sin[d];
        else        r = x * s_cos[d - 64] + qp[d - 64] * s_sin[d - 64];
        s_q[idx] = r * SCALE_LOG2E;
    }
    __syncthreads();

    // ---- q fragments: head = w*G + h, floats l5*4..+3 ----
    v2f q2[G][2];
    #pragma unroll
    for (int h = 0; h < G; ++h) {
        float4 t4 = *(const float4*)&s_q[(w * G + h) * DHEAD + l5 * 4];
        q2[h][0] = v2f{t4.x, t4.y};
        q2[h][1] = v2f{t4.z, t4.w};
    }

    // ---- cache-block bases (wave-uniform SGPRs) ----
    const float* kbase[NCB];
    const float* vbase[NCB];
    const int vofs = half * (HKV * DHEAD) + w * DHEAD + l5 * 4;
    #pragma unroll
    for (int i = 0; i < NCB; ++i) {
        int bt = __builtin_amdgcn_readfirstlane(block_table[b * MAXB + c * NCB + i]);
        kbase[i] = k_cache + (size_t)bt * BLKF + vofs;
        vbase[i] = v_cache + (size_t)bt * BLKF + vofs;
    }

    v2f acc[G][2];
    float lsum[G];
    #pragma unroll
    for (int h = 0; h < G; ++h) {
        lsum[h] = 0.f;
        acc[h][0] = v2f{0.f, 0.f};
        acc[h][1] = v2f{0.f, 0.f};
    }

#define LOADIT(K, V, IT)                                                        \
    do {                                                                        \
        K = *(const float4*)(kbase[(IT) >> 3] + ((IT) & 7) * (2 * HKV * DHEAD));\
        V = *(const float4*)(vbase[(IT) >> 3] + ((IT) & 7) * (2 * HKV * DHEAD));\
    } while (0)

    float4 K0, V0, K1, V1;
    LOADIT(K0, V0, 0);

    #pragma unroll
    for (int IT = 0; IT < NIT; ++IT) {
        if (IT + 1 < NIT) LOADIT(K1, V1, IT + 1);   // depth-2: next in flight
        const int pi = c0 + 2 * IT + half;
        v2f k01 = v2f{K0.x, K0.y}, k23 = v2f{K0.z, K0.w};
        v2f d0 = pk_fma(q2[0][1], k23, pk_mul(q2[0][0], k01));
        v2f d1 = pk_fma(q2[1][1], k23, pk_mul(q2[1][0], k01));
        v2f d2 = pk_fma(q2[2][1], k23, pk_mul(q2[2][0], k01));
        v2f d3 = pk_fma(q2[3][1], k23, pk_mul(q2[3][0], k01));
        float dt0 = d0.x + d0.y, dt1 = d1.x + d1.y;
        float dt2 = d2.x + d2.y, dt3 = d3.x + d3.y;
        ROR4(8, dt0, dt1, dt2, dt3);
        ROR4(4, dt0, dt1, dt2, dt3);
        ROR4(2, dt0, dt1, dt2, dt3);
        ROR4(1, dt0, dt1, dt2, dt3);
        dt0 += __shfl_xor(dt0, 16, 64);
        dt1 += __shfl_xor(dt1, 16, 64);
        dt2 += __shfl_xor(dt2, 16, 64);
        dt3 += __shfl_xor(dt3, 16, 64);
        const bool act = pi < pos;
        float wg0 = act ? fexp2(dt0) : 0.f;
        float wg1 = act ? fexp2(dt1) : 0.f;
        float wg2 = act ? fexp2(dt2) : 0.f;
        float wg3 = act ? fexp2(dt3) : 0.f;
        lsum[0] += wg0; lsum[1] += wg1; lsum[2] += wg2; lsum[3] += wg3;
        v2f u01 = v2f{V0.x, V0.y}, u23 = v2f{V0.z, V0.w};
        acc[0][0] = pk_fma(v2f{wg0, wg0}, u01, acc[0][0]);
        acc[0][1] = pk_fma(v2f{wg0, wg0}, u23, acc[0][1]);
        acc[1][0] = pk_fma(v2f{wg1, wg1}, u01, acc[1][0]);
        acc[1][1] = pk_fma(v2f{wg1, wg1}, u23, acc[1][1]);
        acc[2][0] = pk_fma(v2f{wg2, wg2}, u01, acc[2][0]);
        acc[2][1] = pk_fma(v2f{wg2, wg2}, u23, acc[2][1]);
        acc[3][0] = pk_fma(v2f{wg3, wg3}, u01, acc[3][0]);
        acc[3][1] = pk_fma(v2f{wg3, wg3}, u23, acc[3][1]);
        K0 = K1; V0 = V1;                            // renamed away by unroll
    }
#undef LOADIT

    // ---- merge the two 32-lane halves (distinct positions, same d-slice) ----
    #pragma unroll
    for (int h = 0; h < G; ++h) {
        lsum[h] += __shfl_xor(lsum[h], 32, 64);
        #pragma unroll
        for (int j = 0; j < 2; ++j) {
            float ax = acc[h][j].x, ay = acc[h][j].y;
            ax += __shfl_xor(ax, 32, 64);
            ay += __shfl_xor(ay, 32, 64);
            acc[h][j] = v2f{ax, ay};
        }
    }

    // ---- store: wave w owns slot (b, c, kv=w); lanes 0-31 carry d-slices ----
    if (half == 0) {
        const size_t slot = ((size_t)b * NCHK + c) * HKV + w;
        #pragma unroll
        for (int h = 0; h < G; ++h) {
            float4 o4 = make_float4(acc[h][0].x, acc[h][0].y,
                                    acc[h][1].x, acc[h][1].y);
            *(float4*)&wsacc[slot * (G * DHEAD) + h * DHEAD + l5 * 4] = o4;
        }
        if (l5 == 0) {
            #pragma unroll
            for (int h = 0; h < G; ++h) wsl[slot * G + h] = lsum[h];
        }
    }
}

// ---------------- combine: chunk partials + new-token contribution ----------
template <int PP>
__global__ __launch_bounds__(512) void paged_attn_combine(
    const float* __restrict__ query,
    const float* __restrict__ new_k,
    const float* __restrict__ new_v,
    const int*   __restrict__ context_lens,
    const float* __restrict__ wsacc,
    const float* __restrict__ wsl,
    float*       __restrict__ out)
{
    constexpr int NCHK = LMAX / PP;
    const int bkv = blockIdx.x;
    const int kv  = bkv & 7;
    const int b   = bkv >> 3;
    const int t   = threadIdx.x;
    const int h   = t >> 7;
    const int d   = t & 127;
    const int wv  = t >> 6;

    __shared__ float s_cos[64], s_sin[64], s_kn[DHEAD], s_ps[8];

    const int pos = context_lens[b];
    if (t < 64) {
        float invf = exp2f((float)t * -0.20762050593046014f);
        float ang  = (float)pos * invf;
        s_cos[t] = cosf(ang);
        s_sin[t] = sinf(ang);
    }
    __syncthreads();
    if (t < DHEAD) {
        const float* kp = new_k + ((size_t)b * HKV + kv) * DHEAD;
        float x = kp[t], r;
        if (t < 64) r = x * s_cos[t]      - kp[t + 64] * s_sin[t];
        else        r = x * s_cos[t - 64] + kp[t - 64] * s_sin[t - 64];
        s_kn[t] = r;
    }
    __syncthreads();

    // roped, scaled q for (h, d), then dot with roped k_new
    float rq;
    {
        const float* qp = query + ((size_t)b * HQ + kv * G + h) * DHEAD;
        float x = qp[d];
        if (d < 64) rq = x * s_cos[d]      - qp[d + 64] * s_sin[d];
        else        rq = x * s_cos[d - 64] + qp[d - 64] * s_sin[d - 64];
        rq *= SCALE_LOG2E;
    }
    float part = rq * s_kn[d];
    #pragma unroll
    for (int off = 1; off < 64; off <<= 1) part += __shfl_xor(part, off, 64);
    if ((t & 63) == 0) s_ps[wv] = part;
    __syncthreads();

    const float wnew = fexp2(s_ps[2 * h] + s_ps[2 * h + 1]);

    const int ncc = (pos + PP - 1) / PP;

    float asum = 0.f, lsum = 0.f;
    for (int cc = 0; cc < ncc; cc++) {
        const size_t slot = ((size_t)b * NCHK + cc) * HKV + kv;
        asum += wsacc[slot * (G * DHEAD) + t];
        lsum += wsl[slot * G + h];
    }
    const float vnew = new_v[((size_t)b * HKV + kv) * DHEAD + d];
    out[((size_t)b * HQ + kv * G + h) * DHEAD + d] =
        (asum + wnew * vnew) / (lsum + wnew);
}

extern "C" void kernel_launch(void* const* d_in, const int* in_sizes, int n_in,
                              void* d_out, int out_size, void* d_ws, size_t ws_size,
                              hipStream_t stream) {
    const float* query        = (const float*)d_in[0];
    const float* new_k        = (const float*)d_in[1];
    const float* new_v        = (const float*)d_in[2];
    const float* k_cache      = (const float*)d_in[3];
    const float* v_cache      = (const float*)d_in[4];
    const int*   block_table  = (const int*)d_in[5];
    const int*   context_lens = (const int*)d_in[6];
    float* out = (float*)d_out;

    // P=32 wants 33.8 MB of ws; fall back to P=64 (16.9 MB, proven) if short.
    const size_t slots32 = (size_t)BATCH * (LMAX / 32) * HKV;
    const size_t need32  = slots32 * (G * DHEAD + G) * sizeof(float);

    if (ws_size >= need32) {
        constexpr int PP = 32;
        float* wsacc = (float*)d_ws;
        float* wsl   = wsacc + (size_t)BATCH * (LMAX / PP) * HKV * G * DHEAD;
        paged_attn_chunk<PP><<<dim3(BATCH * (LMAX / PP)), dim3(512), 0, stream>>>(
            query, k_cache, v_cache, block_table, context_lens, wsacc, wsl);
        paged_attn_combine<PP><<<dim3(NBKV), dim3(512), 0, stream>>>(
            query, new_k, new_v, context_lens, wsacc, wsl, out);
    } else {
        constexpr int PP = 64;
        float* wsacc = (float*)d_ws;
        float* wsl   = wsacc + (size_t)BATCH * (LMAX / PP) * HKV * G * DHEAD;
        paged_attn_chunk<PP><<<dim3(BATCH * (LMAX / PP)), dim3(512), 0, stream>>>(
            query, k_cache, v_cache, block_table, context_lens, wsacc, wsl);
        paged_attn_combine<PP><<<dim3(NBKV), dim3(512), 0, stream>>>(
            query, new_k, new_v, context_lens, wsacc, wsl, out);
    }
}

// Round 10
// 87.343 us; speedup vs baseline: 2.1790x; 1.0100x over previous
//
#include <hip/hip_runtime.h>
#include <math.h>

#define BATCH 32
#define HQ 32
#define HKV 8
#define DHEAD 128
#define BS 16
#define MAXB 128
#define G 4
#define CHUNK 256
#define MAXCH 8
#define NW 4
#define NTHR (NW * 64)
#define NSLOT (BATCH * HKV * MAXCH)   // 2048
#define NBKV  (BATCH * HKV)           // 256
#define BLKF  (BS * HKV * DHEAD)      // floats per cache block

#define SCALE_LOG2E 0.12752740305928724f  // (1/sqrt(128)) * log2(e)

typedef float v2f __attribute__((ext_vector_type(2)));
typedef float v4f __attribute__((ext_vector_type(4)));

__device__ __forceinline__ v2f pk_fma(v2f a, v2f b, v2f c) {
    v2f d;
    asm("v_pk_fma_f32 %0, %1, %2, %3" : "=v"(d) : "v"(a), "v"(b), "v"(c));
    return d;
}
__device__ __forceinline__ v2f pk_mul(v2f a, v2f b) {
    v2f d;
    asm("v_pk_mul_f32 %0, %1, %2" : "=v"(d) : "v"(a), "v"(b));
    return d;
}
__device__ __forceinline__ float fexp2(float x) {
    float r;
    asm("v_exp_f32 %0, %1" : "=v"(r) : "v"(x));
    return r;
}
__device__ __forceinline__ v4f ntload(const float* p) {
    return __builtin_nontemporal_load((const v4f*)p);   // global_load_dwordx4 ... nt
}

// rotate-and-add over each 16-lane row, 4 independent chains.
#define ROR4(N, x0, x1, x2, x3)                                                   \
    asm("s_nop 1\n\t"                                                             \
        "v_add_f32_dpp %0, %0, %0 row_ror:" #N " row_mask:0xf bank_mask:0xf\n\t"  \
        "v_add_f32_dpp %1, %1, %1 row_ror:" #N " row_mask:0xf bank_mask:0xf\n\t"  \
        "v_add_f32_dpp %2, %2, %2 row_ror:" #N " row_mask:0xf bank_mask:0xf\n\t"  \
        "v_add_f32_dpp %3, %3, %3 row_ror:" #N " row_mask:0xf bank_mask:0xf"      \
        : "+v"(x0), "+v"(x1), "+v"(x2), "+v"(x3))

// ---------------- chunk: block = (b, kv, 256-position chunk) ----------------
__global__ __launch_bounds__(NTHR) void paged_attn_chunk(
    const float* __restrict__ query,       // [B, HQ, D]
    const float* __restrict__ k_cache,
    const float* __restrict__ v_cache,
    const int*   __restrict__ block_table,
    const int*   __restrict__ context_lens,
    float*       __restrict__ wsacc,       // [NSLOT][G*DHEAD]
    float*       __restrict__ wsl)         // [NSLOT][G]
{
    const int c   = blockIdx.x & (MAXCH - 1);
    const int bkv = blockIdx.x >> 3;
    const int kv  = bkv & 7;
    const int b   = bkv >> 3;

    const int pos = context_lens[b];
    const int c0  = c << 8;
    if (c0 >= pos) return;                 // position 'pos' handled in combine

    const int tid  = threadIdx.x;
    const int w    = tid >> 6;
    const int lane = tid & 63;
    const int grp  = lane >> 4;            // 4 groups: one position each
    const int sub  = lane & 15;            // 8 d-floats: sub*8 .. +7

    __shared__ float s_cos[64], s_sin[64];
    __shared__ float s_q[G * DHEAD];
    __shared__ float s_wacc[NW][G][DHEAD];
    __shared__ float s_wl[NW][G];

    // ---- RoPE tables ----
    if (tid < 64) {
        float invf = exp2f((float)tid * -0.20762050593046014f); // 10000^(-t/64)
        float ang  = (float)pos * invf;
        s_cos[tid] = cosf(ang);
        s_sin[tid] = sinf(ang);
    }
    __syncthreads();

    // ---- roped, scaled q for this block's G heads ----
    for (int idx = tid; idx < G * DHEAD; idx += NTHR) {
        int h = idx >> 7, d = idx & 127;
        const float* qp = query + ((size_t)b * HQ + kv * G + h) * DHEAD;
        float x = qp[d], r;
        if (d < 64) r = x * s_cos[d]      - qp[d + 64] * s_sin[d];
        else        r = x * s_cos[d - 64] + qp[d - 64] * s_sin[d - 64];
        s_q[idx] = r * SCALE_LOG2E;
    }
    __syncthreads();

    // ---- q fragments: 8 floats per lane x 4 heads ----
    v2f q2[G][4];
    #pragma unroll
    for (int h = 0; h < G; ++h) {
        float4 qa = *(const float4*)&s_q[h * DHEAD + sub * 8];
        float4 qc = *(const float4*)&s_q[h * DHEAD + sub * 8 + 4];
        q2[h][0] = v2f{qa.x, qa.y}; q2[h][1] = v2f{qa.z, qa.w};
        q2[h][2] = v2f{qc.x, qc.y}; q2[h][3] = v2f{qc.z, qc.w};
    }

    // ---- wave's active position count & cache-block bases (SGPR) ----
    int a = pos - (c0 + w * 64);
    a = a < 0 ? 0 : (a > 64 ? 64 : a);

    const int tb  = b * MAXB + c * 16 + w * 4;
    const int bt0 = __builtin_amdgcn_readfirstlane(block_table[tb + 0]);
    const int bt1 = __builtin_amdgcn_readfirstlane(block_table[tb + 1]);
    const int bt2 = __builtin_amdgcn_readfirstlane(block_table[tb + 2]);
    const int bt3 = __builtin_amdgcn_readfirstlane(block_table[tb + 3]);

    const int loff = grp * (HKV * DHEAD) + kv * DHEAD + sub * 8;
    const float* kb0 = k_cache + (size_t)bt0 * BLKF + loff;
    const float* kb1 = k_cache + (size_t)bt1 * BLKF + loff;
    const float* kb2 = k_cache + (size_t)bt2 * BLKF + loff;
    const float* kb3 = k_cache + (size_t)bt3 * BLKF + loff;
    const float* vb0 = v_cache + (size_t)bt0 * BLKF + loff;
    const float* vb1 = v_cache + (size_t)bt1 * BLKF + loff;
    const float* vb2 = v_cache + (size_t)bt2 * BLKF + loff;
    const float* vb3 = v_cache + (size_t)bt3 * BLKF + loff;

    v2f acc2[G][4];
    float l[G];
    #pragma unroll
    for (int h = 0; h < G; ++h) {
        l[h] = 0.f;
        #pragma unroll
        for (int j = 0; j < 4; ++j) acc2[h][j] = v2f{0.f, 0.f};
    }

    // one cache block = 16 positions = 4 bodies; loads batched 2 bodies ahead.
#define CBLOCK(KB, VB, CBI)                                                    \
    do {                                                                       \
        _Pragma("unroll")                                                      \
        for (int hb = 0; hb < 2; ++hb) {                                       \
            v4f kk[4], vv[4];                                                  \
            _Pragma("unroll")                                                  \
            for (int i2 = 0; i2 < 2; ++i2) {                                   \
                const int it2 = hb * 2 + i2;                                   \
                kk[2*i2]   = ntload((KB) + it2 * 4096);                        \
                kk[2*i2+1] = ntload((KB) + it2 * 4096 + 4);                    \
                vv[2*i2]   = ntload((VB) + it2 * 4096);                        \
                vv[2*i2+1] = ntload((VB) + it2 * 4096 + 4);                    \
            }                                                                  \
            _Pragma("unroll")                                                  \
            for (int i2 = 0; i2 < 2; ++i2) {                                   \
                const int it2 = hb * 2 + i2;                                   \
                const int pi_ = c0 + w * 64 + (CBI) * 16 + it2 * 4 + grp;      \
                v2f k0_ = v2f{kk[2*i2].x, kk[2*i2].y};                         \
                v2f k1_ = v2f{kk[2*i2].z, kk[2*i2].w};                         \
                v2f k2_ = v2f{kk[2*i2+1].x, kk[2*i2+1].y};                     \
                v2f k3_ = v2f{kk[2*i2+1].z, kk[2*i2+1].w};                     \
                v2f d0_ = pk_fma(q2[0][3], k3_, pk_fma(q2[0][2], k2_,          \
                          pk_fma(q2[0][1], k1_, pk_mul(q2[0][0], k0_))));      \
                v2f d1_ = pk_fma(q2[1][3], k3_, pk_fma(q2[1][2], k2_,          \
                          pk_fma(q2[1][1], k1_, pk_mul(q2[1][0], k0_))));      \
                v2f d2_ = pk_fma(q2[2][3], k3_, pk_fma(q2[2][2], k2_,          \
                          pk_fma(q2[2][1], k1_, pk_mul(q2[2][0], k0_))));      \
                v2f d3_ = pk_fma(q2[3][3], k3_, pk_fma(q2[3][2], k2_,          \
                          pk_fma(q2[3][1], k1_, pk_mul(q2[3][0], k0_))));      \
                float dt0 = d0_.x + d0_.y, dt1 = d1_.x + d1_.y;                \
                float dt2 = d2_.x + d2_.y, dt3 = d3_.x + d3_.y;                \
                ROR4(8, dt0, dt1, dt2, dt3);                                   \
                ROR4(4, dt0, dt1, dt2, dt3);                                   \
                ROR4(2, dt0, dt1, dt2, dt3);                                   \
                ROR4(1, dt0, dt1, dt2, dt3);                                   \
                const bool act_ = pi_ < pos;                                   \
                float wg0 = act_ ? fexp2(dt0) : 0.f;                           \
                float wg1 = act_ ? fexp2(dt1) : 0.f;                           \
                float wg2 = act_ ? fexp2(dt2) : 0.f;                           \
                float wg3 = act_ ? fexp2(dt3) : 0.f;                           \
                l[0] += wg0; l[1] += wg1; l[2] += wg2; l[3] += wg3;            \
                v2f u0_ = v2f{vv[2*i2].x, vv[2*i2].y};                         \
                v2f u1_ = v2f{vv[2*i2].z, vv[2*i2].w};                         \
                v2f u2_ = v2f{vv[2*i2+1].x, vv[2*i2+1].y};                     \
                v2f u3_ = v2f{vv[2*i2+1].z, vv[2*i2+1].w};                     \
                acc2[0][0] = pk_fma(v2f{wg0, wg0}, u0_, acc2[0][0]);           \
                acc2[0][1] = pk_fma(v2f{wg0, wg0}, u1_, acc2[0][1]);           \
                acc2[0][2] = pk_fma(v2f{wg0, wg0}, u2_, acc2[0][2]);           \
                acc2[0][3] = pk_fma(v2f{wg0, wg0}, u3_, acc2[0][3]);           \
                acc2[1][0] = pk_fma(v2f{wg1, wg1}, u0_, acc2[1][0]);           \
                acc2[1][1] = pk_fma(v2f{wg1, wg1}, u1_, acc2[1][1]);           \
                acc2[1][2] = pk_fma(v2f{wg1, wg1}, u2_, acc2[1][2]);           \
                acc2[1][3] = pk_fma(v2f{wg1, wg1}, u3_, acc2[1][3]);           \
                acc2[2][0] = pk_fma(v2f{wg2, wg2}, u0_, acc2[2][0]);           \
                acc2[2][1] = pk_fma(v2f{wg2, wg2}, u1_, acc2[2][1]);           \
                acc2[2][2] = pk_fma(v2f{wg2, wg2}, u2_, acc2[2][2]);           \
                acc2[2][3] = pk_fma(v2f{wg2, wg2}, u3_, acc2[2][3]);           \
                acc2[3][0] = pk_fma(v2f{wg3, wg3}, u0_, acc2[3][0]);           \
                acc2[3][1] = pk_fma(v2f{wg3, wg3}, u1_, acc2[3][1]);           \
                acc2[3][2] = pk_fma(v2f{wg3, wg3}, u2_, acc2[3][2]);           \
                acc2[3][3] = pk_fma(v2f{wg3, wg3}, u3_, acc2[3][3]);           \
            }                                                                  \
        }                                                                      \
    } while (0)

    if (a > 0)  CBLOCK(kb0, vb0, 0);
    if (a > 16) CBLOCK(kb1, vb1, 1);
    if (a > 32) CBLOCK(kb2, vb2, 2);
    if (a > 48) CBLOCK(kb3, vb3, 3);
#undef CBLOCK

    // ---- reduce across the 4 groups ----
    #pragma unroll
    for (int h = 0; h < G; ++h) {
        l[h] += __shfl_xor(l[h], 16, 64);
        l[h] += __shfl_xor(l[h], 32, 64);
        #pragma unroll
        for (int j = 0; j < 4; ++j) {
            float ax = acc2[h][j].x, ay = acc2[h][j].y;
            ax += __shfl_xor(ax, 16, 64); ax += __shfl_xor(ax, 32, 64);
            ay += __shfl_xor(ay, 16, 64); ay += __shfl_xor(ay, 32, 64);
            acc2[h][j] = v2f{ax, ay};
        }
    }
    if (lane < 16) {
        #pragma unroll
        for (int h = 0; h < G; ++h)
            #pragma unroll
            for (int j = 0; j < 4; ++j) {
                s_wacc[w][h][sub * 8 + 2 * j]     = acc2[h][j].x;
                s_wacc[w][h][sub * 8 + 2 * j + 1] = acc2[h][j].y;
            }
    }
    if (lane == 0) {
        #pragma unroll
        for (int h = 0; h < G; ++h) s_wl[w][h] = l[h];
    }
    __syncthreads();

    const size_t slot_base = (size_t)blockIdx.x * (G * DHEAD);
    for (int idx = tid; idx < G * DHEAD; idx += NTHR) {
        float s = s_wacc[0][idx >> 7][idx & 127] + s_wacc[1][idx >> 7][idx & 127]
                + s_wacc[2][idx >> 7][idx & 127] + s_wacc[3][idx >> 7][idx & 127];
        wsacc[slot_base + idx] = s;
    }
    if (tid < G) {
        wsl[(size_t)blockIdx.x * G + tid] =
            s_wl[0][tid] + s_wl[1][tid] + s_wl[2][tid] + s_wl[3][tid];
    }
}

// ---------------- combine: chunk partials + new-token contribution ----------
__global__ __launch_bounds__(512) void paged_attn_combine(
    const float* __restrict__ query,
    const float* __restrict__ new_k,
    const float* __restrict__ new_v,
    const int*   __restrict__ context_lens,
    const float* __restrict__ wsacc,
    const float* __restrict__ wsl,
    float*       __restrict__ out)
{
    const int bkv = blockIdx.x;
    const int kv  = bkv & 7;
    const int b   = bkv >> 3;
    const int t   = threadIdx.x;
    const int h   = t >> 7;
    const int d   = t & 127;
    const int wv  = t >> 6;

    __shared__ float s_cos[64], s_sin[64], s_kn[DHEAD], s_ps[8];

    const int pos = context_lens[b];
    if (t < 64) {
        float invf = exp2f((float)t * -0.20762050593046014f);
        float ang  = (float)pos * invf;
        s_cos[t] = cosf(ang);
        s_sin[t] = sinf(ang);
    }
    __syncthreads();
    if (t < DHEAD) {
        const float* kp = new_k + ((size_t)b * HKV + kv) * DHEAD;
        float x = kp[t], r;
        if (t < 64) r = x * s_cos[t]      - kp[t + 64] * s_sin[t];
        else        r = x * s_cos[t - 64] + kp[t - 64] * s_sin[t - 64];
        s_kn[t] = r;
    }
    __syncthreads();

    // roped, scaled q for (h, d), then dot with roped k_new
    float rq;
    {
        const float* qp = query + ((size_t)b * HQ + kv * G + h) * DHEAD;
        float x = qp[d];
        if (d < 64) rq = x * s_cos[d]      - qp[d + 64] * s_sin[d];
        else        rq = x * s_cos[d - 64] + qp[d - 64] * s_sin[d - 64];
        rq *= SCALE_LOG2E;
    }
    float part = rq * s_kn[d];
    #pragma unroll
    for (int off = 1; off < 64; off <<= 1) part += __shfl_xor(part, off, 64);
    if ((t & 63) == 0) s_ps[wv] = part;
    __syncthreads();

    const float wnew = fexp2(s_ps[2 * h] + s_ps[2 * h + 1]);

    const int ncc = (pos + CHUNK - 1) >> 8;   // chunks holding positions < pos

    float asum = 0.f, lsum = 0.f;
    for (int cc = 0; cc < ncc; cc++) {
        asum += wsacc[((size_t)bkv * MAXCH + cc) * (G * DHEAD) + t];
        lsum += wsl[((size_t)bkv * MAXCH + cc) * G + h];
    }
    const float vnew = new_v[((size_t)b * HKV + kv) * DHEAD + d];
    out[((size_t)b * HQ + kv * G + h) * DHEAD + d] =
        (asum + wnew * vnew) / (lsum + wnew);
}

extern "C" void kernel_launch(void* const* d_in, const int* in_sizes, int n_in,
                              void* d_out, int out_size, void* d_ws, size_t ws_size,
                              hipStream_t stream) {
    const float* query        = (const float*)d_in[0];
    const float* new_k        = (const float*)d_in[1];
    const float* new_v        = (const float*)d_in[2];
    const float* k_cache      = (const float*)d_in[3];
    const float* v_cache      = (const float*)d_in[4];
    const int*   block_table  = (const int*)d_in[5];
    const int*   context_lens = (const int*)d_in[6];
    float* out = (float*)d_out;

    float* wsacc = (float*)d_ws;                          // NSLOT*512
    float* wsl   = wsacc + (size_t)NSLOT * G * DHEAD;     // NSLOT*4

    paged_attn_chunk<<<dim3(NSLOT), dim3(NTHR), 0, stream>>>(
        query, k_cache, v_cache, block_table, context_lens, wsacc, wsl);
    paged_attn_combine<<<dim3(NBKV), dim3(512), 0, stream>>>(
        query, new_k, new_v, context_lens, wsacc, wsl, out);
}